// Round 3
// baseline (15305.611 us; speedup 1.0000x reference)
//
#include <hip/hip_runtime.h>
#include <cstdint>
#include <cstddef>

#define B_  64
#define T_  512
#define I_  256
#define H_  1024
#define O_  10
#define ZS  68   // z LDS row stride (floats): 2-way bank aliasing = free

typedef __attribute__((ext_vector_type(4))) float f32x4;
typedef __attribute__((ext_vector_type(8))) short s16x8;

__device__ inline unsigned short f2bf(float f) {
    unsigned int u = __float_as_uint(f);
    u += 0x7fffu + ((u >> 16) & 1u);     // round-to-nearest-even
    return (unsigned short)(u >> 16);
}
__device__ inline float bf2f(unsigned short h) {
    return __uint_as_float(((unsigned int)h) << 16);
}
__device__ inline float fsig(float x)  { return 1.0f / (1.0f + __expf(-x)); }
__device__ inline float ftanh(float x) { return 1.0f - 2.0f / (1.0f + __expf(2.0f * x)); }

// ---------------------------------------------------------------- prolog packs
// xb[t][b][i] (bf16)  <-  x[b][t][i] (fp32)
__global__ __launch_bounds__(256) void cast_xT_kernel(const float* __restrict__ x,
                                                      unsigned short* __restrict__ xb) {
    int idx = blockIdx.x * 256 + threadIdx.x;          // 2,097,152 ushort4 items
    int ic4 = idx & 63, rest = idx >> 6;
    int t = rest & 511, b = rest >> 9;
    float4 v = ((const float4*)x)[((size_t)(b * T_ + t)) * 64 + ic4];
    ((ushort4*)xb)[((size_t)(t * B_ + b)) * 64 + ic4] =
        make_ushort4(f2bf(v.x), f2bf(v.y), f2bf(v.z), f2bf(v.w));
}

// Pack Wh into per-block/wave MFMA B-fragments.
// e = nb*8192 + kt*256 + w*64 + lane; col n_local=lane&15 -> q=n_local>>2, cc=n_local&3,
// h' = nb*16 + w*4 + cc;  k = kt*32 + (lane>>4)*8 + j.
__global__ __launch_bounds__(256) void pack_wh_kernel(const float* __restrict__ Wh,
                                                      uint4* __restrict__ whp) {
    int e = blockIdx.x * 256 + threadIdx.x;            // 524,288
    int lane = e & 63, w = (e >> 6) & 3, kt = (e >> 8) & 31, nb = e >> 13;
    int q = (lane & 15) >> 2, cc = lane & 3;
    int hh = nb * 16 + w * 4 + cc;
    int k0 = kt * 32 + (lane >> 4) * 8;
    const float* src = Wh + (size_t)q * (H_ * H_) + (size_t)k0 * H_ + hh;
    unsigned short u[8];
#pragma unroll
    for (int j = 0; j < 8; ++j) u[j] = f2bf(src[(size_t)j * H_]);
    uint4 out;
    out.x = (unsigned)u[0] | ((unsigned)u[1] << 16);
    out.y = (unsigned)u[2] | ((unsigned)u[3] << 16);
    out.z = (unsigned)u[4] | ((unsigned)u[5] << 16);
    out.w = (unsigned)u[6] | ((unsigned)u[7] << 16);
    whp[e] = out;
}

// Same fragment pack for Wx (K = 256 -> 8 kt).
__global__ __launch_bounds__(256) void pack_wx_kernel(const float* __restrict__ Wx,
                                                      uint4* __restrict__ wxp) {
    int e = blockIdx.x * 256 + threadIdx.x;            // 131,072
    int lane = e & 63, w = (e >> 6) & 3, kt = (e >> 8) & 7, nb = e >> 11;
    int q = (lane & 15) >> 2, cc = lane & 3;
    int hh = nb * 16 + w * 4 + cc;
    int i0 = kt * 32 + (lane >> 4) * 8;
    const float* src = Wx + (size_t)q * (I_ * H_) + (size_t)i0 * H_ + hh;
    unsigned short u[8];
#pragma unroll
    for (int j = 0; j < 8; ++j) u[j] = f2bf(src[(size_t)j * H_]);
    uint4 out;
    out.x = (unsigned)u[0] | ((unsigned)u[1] << 16);
    out.y = (unsigned)u[2] | ((unsigned)u[3] << 16);
    out.z = (unsigned)u[4] | ((unsigned)u[5] << 16);
    out.w = (unsigned)u[6] | ((unsigned)u[7] << 16);
    wxp[e] = out;
}

// ---------------------------------------------------------------- persistent LSTM
// 64 blocks (block nb owns h-columns nb*16..nb*16+15, all 4 gates = 64 z-cols).
// Wh fragments resident in VGPRs (32 kt x 4 VGPR = 128), Wx fragments too (8 kt = 32).
// Input projection for step t+1 computed in the sync shadow; biases folded into acc init.
__global__ __launch_bounds__(256, 1) void lstm_kernel(const unsigned short* __restrict__ xb,
                                                      const uint4* __restrict__ whp,
                                                      const uint4* __restrict__ wxp,
                                                      const float* __restrict__ bx,
                                                      const float* __restrict__ bh,
                                                      const float* __restrict__ Wp,
                                                      const float* __restrict__ bp,
                                                      unsigned short* __restrict__ hbuf,
                                                      unsigned int* __restrict__ flags,
                                                      float* __restrict__ out) {
    __shared__ float zbuf[64 * ZS];      // 17.4 KB total LDS
    int tid = threadIdx.x, lane = tid & 63, w = tid >> 6;
    int nb = blockIdx.x;
    int ma = lane & 15, quad = lane >> 4, qa = quad * 8;

    // resident weight fragments
    const s16x8* whpp = (const s16x8*)whp;
    const s16x8* wxpp = (const s16x8*)wxp;
    s16x8 whf[32], wxf[8];
#pragma unroll
    for (int kt = 0; kt < 32; ++kt) whf[kt] = whpp[nb * 8192 + kt * 256 + w * 64 + lane];
#pragma unroll
    for (int kt = 0; kt < 8; ++kt)  wxf[kt] = wxpp[nb * 2048 + kt * 256 + w * 64 + lane];

    // per-lane bias (constant over batch rows): n = q*1024 + nb*16 + w*4 + cc
    {
    }
    int q_l = ma >> 2, cc_l = ma & 3;
    int ncol = q_l * H_ + nb * 16 + w * 4 + cc_l;
    float biasv = bx[ncol] + bh[ncol];

    // init h0 slice, post flag 1
    int gb = tid >> 2, wq = tid & 3;
    int hcol = nb * 16 + wq * 4;
    *(ushort4*)(hbuf + gb * H_ + hcol) = make_ushort4(0, 0, 0, 0);
    float cst[4] = {0.f, 0.f, 0.f, 0.f};
    __threadfence();
    __syncthreads();
    if (tid == 0)
        __hip_atomic_store(&flags[nb * 16], 1u, __ATOMIC_RELEASE, __HIP_MEMORY_SCOPE_AGENT);

    // shadow-compute gx(0)
    f32x4 gxacc[4];
#pragma unroll
    for (int mt = 0; mt < 4; ++mt) gxacc[mt] = (f32x4){biasv, biasv, biasv, biasv};
#pragma unroll
    for (int kt = 0; kt < 8; ++kt)
#pragma unroll
        for (int mt = 0; mt < 4; ++mt) {
            const s16x8* ap = (const s16x8*)(xb + (size_t)(mt * 16 + ma) * I_ + kt * 32 + qa);
            gxacc[mt] = __builtin_amdgcn_mfma_f32_16x16x32_bf16(*ap, wxf[kt], gxacc[mt], 0, 0, 0);
        }

    unsigned short* h0 = hbuf;
    unsigned short* h1 = hbuf + B_ * H_;
    int sl = tid & 63;

    for (int t = 0; t < T_; ++t) {
        // wait until all blocks published h(t-1)
        unsigned int tgt = (unsigned)(t + 1);
        while (__hip_atomic_load(&flags[sl * 16], __ATOMIC_RELAXED, __HIP_MEMORY_SCOPE_AGENT) < tgt) {}
        __threadfence();   // acquire
        __syncthreads();

        const unsigned short* hp = (t & 1) ? h1 : h0;
        unsigned short* hn = (t & 1) ? h0 : h1;

        // z = gx(t) + h(t-1) @ WhSlice  (M=64, N=16/wave, K=1024)
        f32x4 acc[4];
#pragma unroll
        for (int mt = 0; mt < 4; ++mt) acc[mt] = gxacc[mt];
#pragma unroll
        for (int kt = 0; kt < 32; ++kt)
#pragma unroll
            for (int mt = 0; mt < 4; ++mt) {
                const s16x8* ap = (const s16x8*)(hp + (size_t)(mt * 16 + ma) * H_ + kt * 32 + qa);
                acc[mt] = __builtin_amdgcn_mfma_f32_16x16x32_bf16(*ap, whf[kt], acc[mt], 0, 0, 0);
            }

        // transpose z through LDS: C layout row = quad*4+r (batch), col = n_local
        int coll = w * 16 + ma;
#pragma unroll
        for (int mt = 0; mt < 4; ++mt)
#pragma unroll
            for (int r = 0; r < 4; ++r)
                zbuf[(mt * 16 + quad * 4 + r) * ZS + coll] = acc[mt][r];
        __syncthreads();

        // gates: thread (gb, wq) owns (b=gb, h' = nb*16 + wq*4 + i)
        const float4* zrow = (const float4*)(zbuf + gb * ZS + wq * 16);
        float4 zg = zrow[0], zi = zrow[1], zf = zrow[2], zo = zrow[3];
        float zga[4] = {zg.x, zg.y, zg.z, zg.w};
        float zia[4] = {zi.x, zi.y, zi.z, zi.w};
        float zfa[4] = {zf.x, zf.y, zf.z, zf.w};
        float zoa[4] = {zo.x, zo.y, zo.z, zo.w};
        unsigned short hh[4];
#pragma unroll
        for (int i = 0; i < 4; ++i) {
            float g  = ftanh(zga[i]);
            float ii = fsig (zia[i]);
            float ff = fsig (zfa[i]);
            float oo = fsig (zoa[i]);
            float c  = g * ii + cst[i] * ff;
            cst[i] = c;
            hh[i] = f2bf(ftanh(c) * oo);
        }
        *(ushort4*)(hn + gb * H_ + hcol) = make_ushort4(hh[0], hh[1], hh[2], hh[3]);

        __threadfence();   // release h(t)
        __syncthreads();
        if (tid == 0)
            __hip_atomic_store(&flags[nb * 16], (unsigned)(t + 2), __ATOMIC_RELEASE, __HIP_MEMORY_SCOPE_AGENT);

        // shadow: gx(t+1) (input projection; independent of h -> hidden in sync shadow)
        int ts = (t < T_ - 1) ? t + 1 : T_ - 1;
#pragma unroll
        for (int mt = 0; mt < 4; ++mt) gxacc[mt] = (f32x4){biasv, biasv, biasv, biasv};
#pragma unroll
        for (int kt = 0; kt < 8; ++kt)
#pragma unroll
            for (int mt = 0; mt < 4; ++mt) {
                const s16x8* ap = (const s16x8*)(xb + ((size_t)(ts * B_ + mt * 16 + ma)) * I_ + kt * 32 + qa);
                gxacc[mt] = __builtin_amdgcn_mfma_f32_16x16x32_bf16(*ap, wxf[kt], gxacc[mt], 0, 0, 0);
            }
    }

    // final wait: all blocks' h(511) visible
    {
        unsigned int tgt = (unsigned)(T_ + 1);
        while (__hip_atomic_load(&flags[sl * 16], __ATOMIC_RELAXED, __HIP_MEMORY_SCOPE_AGENT) < tgt) {}
        __threadfence();
        __syncthreads();
    }

    // ---------------- projection + softmax: block nb handles batch row nb
    int b = nb;
    const unsigned short* hT = h0;       // t=511 (odd) wrote into h0
    float pacc[O_];
#pragma unroll
    for (int o = 0; o < O_; ++o) pacc[o] = 0.f;
    for (int s = 0; s < 4; ++s) {
        int j = s * 256 + tid;
        float hv = bf2f(hT[b * H_ + j]);
        const float* wr = Wp + (size_t)j * O_;
#pragma unroll
        for (int o = 0; o < O_; ++o) pacc[o] += hv * wr[o];
    }
    float* red = zbuf;
#pragma unroll
    for (int o = 0; o < O_; ++o) red[tid * O_ + o] = pacc[o];
    __syncthreads();
    for (int s2 = 128; s2 > 0; s2 >>= 1) {
        if (tid < s2) {
#pragma unroll
            for (int o = 0; o < O_; ++o) red[tid * O_ + o] += red[(tid + s2) * O_ + o];
        }
        __syncthreads();
    }
    if (tid == 0) {
        float p[O_];
        for (int o = 0; o < O_; ++o) p[o] = red[o] + bp[o];
        float mx = p[0];
        for (int o = 1; o < O_; ++o) mx = fmaxf(mx, p[o]);
        float e[O_], sum = 0.f;
        for (int o = 0; o < O_; ++o) { e[o] = __expf(p[o] - mx); sum += e[o]; }
        float inv = 1.f / sum;
        for (int o = 0; o < O_; ++o) out[b * O_ + o] = e[o] * inv;
    }
}

// ---------------------------------------------------------------- launch
extern "C" void kernel_launch(void* const* d_in, const int* in_sizes, int n_in,
                              void* d_out, int out_size, void* d_ws, size_t ws_size,
                              hipStream_t stream) {
    (void)in_sizes; (void)n_in; (void)out_size; (void)ws_size;
    const float* x  = (const float*)d_in[0];
    const float* Wx = (const float*)d_in[1];
    const float* bx = (const float*)d_in[2];
    const float* Wh = (const float*)d_in[3];
    const float* bh = (const float*)d_in[4];
    const float* Wp = (const float*)d_in[5];
    const float* bp = (const float*)d_in[6];

    const size_t xbB  = (size_t)T_ * B_ * I_ * 2;      // 16 MB
    const size_t whpB = (size_t)4 * H_ * H_ * 2;       // 8 MB
    const size_t wxpB = (size_t)4 * I_ * H_ * 2;       // 2 MB
    const size_t hB   = (size_t)2 * B_ * H_ * 2;       // 256 KB

    char* ws = (char*)d_ws;
    unsigned short* xb    = (unsigned short*)ws;
    uint4*          whp   = (uint4*)(ws + xbB);
    uint4*          wxp   = (uint4*)(ws + xbB + whpB);
    unsigned short* hbuf  = (unsigned short*)(ws + xbB + whpB + wxpB);
    unsigned int*   flags = (unsigned int*)(ws + xbB + whpB + wxpB + hB);

    hipError_t e0 = hipMemsetAsync(flags, 0, 4096, stream);
    (void)e0;
    cast_xT_kernel<<<8192, 256, 0, stream>>>(x, xb);
    pack_wh_kernel<<<2048, 256, 0, stream>>>(Wh, whp);
    pack_wx_kernel<<< 512, 256, 0, stream>>>(Wx, wxp);
    lstm_kernel<<<64, 256, 0, stream>>>(xb, whp, wxp, bx, bh, Wp, bp, hbuf, flags,
                                        (float*)d_out);
}

// Round 4
// 5885.651 us; speedup vs baseline: 2.6005x; 2.6005x over previous
//
#include <hip/hip_runtime.h>
#include <cstdint>
#include <cstddef>

#define B_  64
#define T_  512
#define I_  256
#define H_  1024
#define O_  10
#define ZST 68              // zpart row stride (f32)
#define ZPW (64 * ZST)      // per-wave partial block (floats)
#define LDS_BYTES (4 * ZPW * 4)

typedef __attribute__((ext_vector_type(4))) float f32x4;
typedef __attribute__((ext_vector_type(8))) short s16x8;
typedef unsigned long long u64;

__device__ inline unsigned short f2bf(float f) {
    unsigned int u = __float_as_uint(f);
    u += 0x7fffu + ((u >> 16) & 1u);     // round-to-nearest-even
    return (unsigned short)(u >> 16);
}
__device__ inline float bf2f(unsigned short h) {
    return __uint_as_float(((unsigned int)h) << 16);
}
__device__ inline float fsig(float x)  { return 1.0f / (1.0f + __expf(-x)); }
__device__ inline float ftanh(float x) { return 1.0f - 2.0f / (1.0f + __expf(2.0f * x)); }

#define ALD(p) __hip_atomic_load((p), __ATOMIC_RELAXED, __HIP_MEMORY_SCOPE_AGENT)
#define AST(p, v) __hip_atomic_store((p), (v), __ATOMIC_RELAXED, __HIP_MEMORY_SCOPE_AGENT)

// ---------------------------------------------------------------- prolog packs
// xb[t][b][i] (bf16)  <-  x[b][t][i] (fp32)
__global__ __launch_bounds__(256) void cast_xT_kernel(const float* __restrict__ x,
                                                      unsigned short* __restrict__ xb) {
    int idx = blockIdx.x * 256 + threadIdx.x;          // 2,097,152 ushort4 items
    int ic4 = idx & 63, rest = idx >> 6;
    int t = rest & 511, b = rest >> 9;
    float4 v = ((const float4*)x)[((size_t)(b * T_ + t)) * 64 + ic4];
    ((ushort4*)xb)[((size_t)(t * B_ + b)) * 64 + ic4] =
        make_ushort4(f2bf(v.x), f2bf(v.y), f2bf(v.z), f2bf(v.w));
}

// Pack Wh into MFMA B-fragments: e = nb*8192 + kt*256 + nt*64 + lane.
// col n_local = lane&15 -> gate q = n_local>>2, cc = n_local&3; h' = nb*16 + nt*4 + cc;
// k = kt*32 + (lane>>4)*8 + j.
__global__ __launch_bounds__(256) void pack_wh_kernel(const float* __restrict__ Wh,
                                                      uint4* __restrict__ whp) {
    int e = blockIdx.x * 256 + threadIdx.x;            // 524,288
    int lane = e & 63, nt = (e >> 6) & 3, kt = (e >> 8) & 31, nb = e >> 13;
    int q = (lane & 15) >> 2, cc = lane & 3;
    int hh = nb * 16 + nt * 4 + cc;
    int k0 = kt * 32 + (lane >> 4) * 8;
    const float* src = Wh + (size_t)q * (H_ * H_) + (size_t)k0 * H_ + hh;
    unsigned short u[8];
#pragma unroll
    for (int j = 0; j < 8; ++j) u[j] = f2bf(src[(size_t)j * H_]);
    uint4 out;
    out.x = (unsigned)u[0] | ((unsigned)u[1] << 16);
    out.y = (unsigned)u[2] | ((unsigned)u[3] << 16);
    out.z = (unsigned)u[4] | ((unsigned)u[5] << 16);
    out.w = (unsigned)u[6] | ((unsigned)u[7] << 16);
    whp[e] = out;
}

// Same fragment pack for Wx (K = 256 -> 8 kt).
__global__ __launch_bounds__(256) void pack_wx_kernel(const float* __restrict__ Wx,
                                                      uint4* __restrict__ wxp) {
    int e = blockIdx.x * 256 + threadIdx.x;            // 131,072
    int lane = e & 63, nt = (e >> 6) & 3, kt = (e >> 8) & 7, nb = e >> 11;
    int q = (lane & 15) >> 2, cc = lane & 3;
    int hh = nb * 16 + nt * 4 + cc;
    int i0 = kt * 32 + (lane >> 4) * 8;
    const float* src = Wx + (size_t)q * (I_ * H_) + (size_t)i0 * H_ + hh;
    unsigned short u[8];
#pragma unroll
    for (int j = 0; j < 8; ++j) u[j] = f2bf(src[(size_t)j * H_]);
    uint4 out;
    out.x = (unsigned)u[0] | ((unsigned)u[1] << 16);
    out.y = (unsigned)u[2] | ((unsigned)u[3] << 16);
    out.z = (unsigned)u[4] | ((unsigned)u[5] << 16);
    out.w = (unsigned)u[6] | ((unsigned)u[7] << 16);
    wxp[e] = out;
}

// ---------------------------------------------------------------- persistent LSTM
// 64 blocks; block nb owns h-cols [nb*16, nb*16+16) (x4 gates = 64 z-cols).
// K-split across waves: wave w covers h-K [w*256,+256) and x-K [w*64,+64).
// All cross-block h traffic via relaxed AGENT atomics (per-access LLC coherence,
// NO cache-wide fences). Partial z reduced through LDS.
__global__ __launch_bounds__(256, 1) void lstm_kernel(const unsigned short* __restrict__ xb,
                                                      const uint4* __restrict__ whp,
                                                      const uint4* __restrict__ wxp,
                                                      const float* __restrict__ bx,
                                                      const float* __restrict__ bh,
                                                      const float* __restrict__ Wp,
                                                      const float* __restrict__ bp,
                                                      unsigned short* __restrict__ hbuf,
                                                      unsigned int* __restrict__ flags,
                                                      float* __restrict__ out) {
    extern __shared__ float zpart[];     // [4][64][ZST] = 69632 B (dynamic LDS)
    int tid = threadIdx.x, lane = tid & 63, w = tid >> 6;
    int nb = blockIdx.x;
    int ma = lane & 15, quad = lane >> 4;

    // resident weight fragments (B-operands)
    const s16x8* whpp = (const s16x8*)whp;
    const s16x8* wxpp = (const s16x8*)wxp;
    s16x8 whf[4][8], wxf[4][2];
#pragma unroll
    for (int nt = 0; nt < 4; ++nt) {
#pragma unroll
        for (int k = 0; k < 8; ++k)
            whf[nt][k] = whpp[nb * 8192 + (w * 8 + k) * 256 + nt * 64 + lane];
#pragma unroll
        for (int k = 0; k < 2; ++k)
            wxf[nt][k] = wxpp[nb * 2048 + (w * 2 + k) * 256 + nt * 64 + lane];
    }

    // gate-stage ownership: thread (gb, wq) -> batch gb, h-cols nb*16+wq*4..+4
    int gb = tid >> 2, wq = tid & 3;
    int hcol = nb * 16 + wq * 4;
    float bias[4][4];
#pragma unroll
    for (int g = 0; g < 4; ++g)
#pragma unroll
        for (int i = 0; i < 4; ++i) {
            int n = g * H_ + hcol + i;
            bias[g][i] = bx[n] + bh[n];
        }

    u64* h0 = (u64*)hbuf;                // 16384 u64 per buffer
    u64* h1 = h0 + (B_ * H_ / 4);

    // h0 init slice + publish flag 1
    AST(&h0[gb * 256 + nb * 4 + wq], 0ull);
    __syncthreads();                     // drains vmcnt before barrier
    if (tid == 0) AST(&flags[nb * 16], 1u);

    float cst[4] = {0.f, 0.f, 0.f, 0.f};

    for (int t = 0; t < T_; ++t) {
        // ---- wait until all blocks published h(t-1)
        if (w == 0) {
            unsigned int tgt = (unsigned)(t + 1);
            while (ALD(&flags[lane * 16]) < tgt) {}
        }
        __syncthreads();

        const u64* hp = (t & 1) ? h1 : h0;
        u64* hn = (t & 1) ? h0 : h1;

        // ---- z partial: [64 batch x 64 cols] over this wave's K slice
        f32x4 acc[4][4] = {};
        u64 Ah[2][16];
        s16x8 Ax[2][2];

#define LOADA(mt, buf)                                                          \
        {                                                                       \
            int row = (mt) * 16 + ma;                                           \
            const u64* hrow = hp + row * 256 + w * 64 + quad * 2;               \
            _Pragma("unroll")                                                   \
            for (int kl = 0; kl < 8; ++kl) {                                    \
                Ah[buf][kl * 2]     = ALD(hrow + kl * 8);                       \
                Ah[buf][kl * 2 + 1] = ALD(hrow + kl * 8 + 1);                   \
            }                                                                   \
            const unsigned short* xrow =                                        \
                xb + ((size_t)t * B_ + row) * I_ + w * 64 + quad * 8;           \
            Ax[buf][0] = *(const s16x8*)xrow;                                   \
            Ax[buf][1] = *(const s16x8*)(xrow + 32);                            \
        }

        LOADA(0, 0)
#pragma unroll
        for (int mt = 0; mt < 4; ++mt) {
            int cur = mt & 1;
            if (mt == 0) LOADA(1, 1)
            if (mt == 1) LOADA(2, 0)
            if (mt == 2) LOADA(3, 1)
#pragma unroll
            for (int kl = 0; kl < 8; ++kl) {
                union { u64 q[2]; s16x8 v; } au;
                au.q[0] = Ah[cur][kl * 2];
                au.q[1] = Ah[cur][kl * 2 + 1];
#pragma unroll
                for (int nt = 0; nt < 4; ++nt)
                    acc[mt][nt] = __builtin_amdgcn_mfma_f32_16x16x32_bf16(au.v, whf[nt][kl],
                                                                          acc[mt][nt], 0, 0, 0);
            }
#pragma unroll
            for (int kx = 0; kx < 2; ++kx)
#pragma unroll
                for (int nt = 0; nt < 4; ++nt)
                    acc[mt][nt] = __builtin_amdgcn_mfma_f32_16x16x32_bf16(Ax[cur][kx], wxf[nt][kx],
                                                                          acc[mt][nt], 0, 0, 0);
        }
#undef LOADA

        // ---- write partial to LDS (C layout: row=quad*4+r, col=ma per 16x16 tile)
        float* zp = zpart + w * ZPW;
#pragma unroll
        for (int mt = 0; mt < 4; ++mt)
#pragma unroll
            for (int nt = 0; nt < 4; ++nt)
#pragma unroll
                for (int r = 0; r < 4; ++r)
                    zp[(mt * 16 + quad * 4 + r) * ZST + nt * 16 + ma] = acc[mt][nt][r];
        __syncthreads();

        // ---- gates: sum 4 partials, z col = wq*16 + g*4 + i
        float zs[4][4];
#pragma unroll
        for (int g = 0; g < 4; ++g) {
            float4 s = make_float4(0.f, 0.f, 0.f, 0.f);
#pragma unroll
            for (int p = 0; p < 4; ++p) {
                float4 v = *(const float4*)(zpart + p * ZPW + gb * ZST + wq * 16 + g * 4);
                s.x += v.x; s.y += v.y; s.z += v.z; s.w += v.w;
            }
            zs[g][0] = s.x; zs[g][1] = s.y; zs[g][2] = s.z; zs[g][3] = s.w;
        }
        unsigned short hh[4];
#pragma unroll
        for (int i = 0; i < 4; ++i) {
            float g  = ftanh(zs[0][i] + bias[0][i]);
            float ii = fsig (zs[1][i] + bias[1][i]);
            float ff = fsig (zs[2][i] + bias[2][i]);
            float oo = fsig (zs[3][i] + bias[3][i]);
            float c  = g * ii + cst[i] * ff;
            cst[i] = c;
            hh[i] = f2bf(ftanh(c) * oo);
        }
        u64 hv = (u64)hh[0] | ((u64)hh[1] << 16) | ((u64)hh[2] << 32) | ((u64)hh[3] << 48);
        AST(&hn[gb * 256 + nb * 4 + wq], hv);

        __syncthreads();                 // drain stores (vmcnt(0) before s_barrier)
        if (tid == 0) AST(&flags[nb * 16], (unsigned)(t + 2));
    }

    // final wait: all blocks' h(511) visible
    if (w == 0) {
        while (ALD(&flags[lane * 16]) < (unsigned)(T_ + 1)) {}
    }
    __syncthreads();

    // ---------------- projection + softmax: block nb handles batch row nb
    int b = nb;
    union { u64 q; unsigned short s[4]; } hu;
    hu.q = ALD(&h0[b * 256 + tid]);      // t=511 wrote into h0
    float pacc[O_];
#pragma unroll
    for (int o = 0; o < O_; ++o) pacc[o] = 0.f;
#pragma unroll
    for (int j = 0; j < 4; ++j) {
        float hvv = bf2f(hu.s[j]);
        const float* wr = Wp + (size_t)(tid * 4 + j) * O_;
#pragma unroll
        for (int o = 0; o < O_; ++o) pacc[o] += hvv * wr[o];
    }
    float* red = zpart;
#pragma unroll
    for (int o = 0; o < O_; ++o) red[tid * O_ + o] = pacc[o];
    __syncthreads();
    for (int s2 = 128; s2 > 0; s2 >>= 1) {
        if (tid < s2) {
#pragma unroll
            for (int o = 0; o < O_; ++o) red[tid * O_ + o] += red[(tid + s2) * O_ + o];
        }
        __syncthreads();
    }
    if (tid == 0) {
        float p[O_];
        for (int o = 0; o < O_; ++o) p[o] = red[o] + bp[o];
        float mx = p[0];
        for (int o = 1; o < O_; ++o) mx = fmaxf(mx, p[o]);
        float e[O_], sum = 0.f;
        for (int o = 0; o < O_; ++o) { e[o] = __expf(p[o] - mx); sum += e[o]; }
        float inv = 1.f / sum;
        for (int o = 0; o < O_; ++o) out[b * O_ + o] = e[o] * inv;
    }
}

// ---------------------------------------------------------------- launch
extern "C" void kernel_launch(void* const* d_in, const int* in_sizes, int n_in,
                              void* d_out, int out_size, void* d_ws, size_t ws_size,
                              hipStream_t stream) {
    (void)in_sizes; (void)n_in; (void)out_size; (void)ws_size;
    const float* x  = (const float*)d_in[0];
    const float* Wx = (const float*)d_in[1];
    const float* bx = (const float*)d_in[2];
    const float* Wh = (const float*)d_in[3];
    const float* bh = (const float*)d_in[4];
    const float* Wp = (const float*)d_in[5];
    const float* bp = (const float*)d_in[6];

    const size_t xbB  = (size_t)T_ * B_ * I_ * 2;      // 16 MB
    const size_t whpB = (size_t)4 * H_ * H_ * 2;       // 8 MB
    const size_t wxpB = (size_t)4 * I_ * H_ * 2;       // 2 MB
    const size_t hB   = (size_t)2 * B_ * H_ * 2;       // 256 KB

    char* ws = (char*)d_ws;
    unsigned short* xb    = (unsigned short*)ws;
    uint4*          whp   = (uint4*)(ws + xbB);
    uint4*          wxp   = (uint4*)(ws + xbB + whpB);
    unsigned short* hbuf  = (unsigned short*)(ws + xbB + whpB + wxpB);
    unsigned int*   flags = (unsigned int*)(ws + xbB + whpB + wxpB + hB);

    static bool attr_set = false;
    if (!attr_set) {
        (void)hipFuncSetAttribute((const void*)lstm_kernel,
                                  hipFuncAttributeMaxDynamicSharedMemorySize, LDS_BYTES);
        attr_set = true;
    }

    hipError_t e0 = hipMemsetAsync(flags, 0, 4096, stream);
    (void)e0;
    cast_xT_kernel<<<8192, 256, 0, stream>>>(x, xb);
    pack_wh_kernel<<<2048, 256, 0, stream>>>(Wh, whp);
    pack_wx_kernel<<< 512, 256, 0, stream>>>(Wx, wxp);
    lstm_kernel<<<64, 256, LDS_BYTES, stream>>>(xb, whp, wxp, bx, bh, Wp, bp, hbuf, flags,
                                                (float*)d_out);
}